// Round 14
// baseline (101.604 us; speedup 1.0000x reference)
//
#include <hip/hip_runtime.h>
#include <math.h>

// Problem constants (fixed by setup_inputs)
#define BB  16      // batch
#define SS  1024    // spans
#define CC  16      // candidates per span
#define LL  256     // unique links
#define SCW 1041    // 1 + CC + SS  (scores row width)
#define NTAB 5000   // candidate/link id space

#define TCH 16                    // t-rows per matvec chunk
#define NCH (SS / TCH)            // 64 chunks per batch
#define NT  (SS / 64)             // 16 tiles per axis in tr2
#define NTRI (NT * (NT + 1) / 2)  // 136 upper-tri tiles per batch

// ---------------------------------------------------------------------------
// fp8 e4m3 (OCP) encode/decode, self-contained bit ops.  Our W values are
// either exactly 0 (diag) or in [~0.05, ~16] -- always e4m3-normal.
// encode: RNE into 3-bit mantissa; flush-to-zero below 2^-6 (unreachable).
__device__ __forceinline__ unsigned char enc8(float f) {
    unsigned u = __float_as_uint(f);
    if (u < 0x3C800000u) return 0;       // < 2^-6 (incl. exact 0) -> 0
    u += 0x7FFFFu + ((u >> 20) & 1u);    // round-to-nearest-even into man3
    return (unsigned char)((u >> 20) - 960u);   // ((e8-120)<<3)|man3
}
// decode: byte b = (e<<3)|m (e>=1)  ->  f32 bits ((e+120)<<23)|(m<<20)
__device__ __forceinline__ float dec8(unsigned char b) {
    return b ? __uint_as_float(((unsigned)b + 960u) << 20) : 0.0f;
}

// ---------------------------------------------------------------------------
// block-wide sum reduction (blockDim multiple of 64, <=1024), lds >= 16 floats
__device__ __forceinline__ float blockReduceSum(float v, float* lds) {
#pragma unroll
    for (int o = 32; o > 0; o >>= 1) v += __shfl_down(v, o, 64);
    int lane = threadIdx.x & 63;
    int wid  = threadIdx.x >> 6;
    int nw   = blockDim.x >> 6;
    if (lane == 0) lds[wid] = v;
    __syncthreads();
    v = (threadIdx.x < nw) ? lds[threadIdx.x] : 0.0f;
    if (wid == 0) {
#pragma unroll
        for (int o = 8; o > 0; o >>= 1) v += __shfl_down(v, o, 64);
        if (lane == 0) lds[0] = v;
    }
    __syncthreads();
    v = lds[0];
    __syncthreads();
    return v;
}

// ---------------------------------------------------------------------------
// Per-batch setup: block b zeroes its own cnt slice, xA/xB slices, part slice;
// then counts link multiplicities.
__global__ __launch_bounds__(256) void kCnt(const int* __restrict__ ul,
                                            int*   __restrict__ cnt,
                                            float* __restrict__ xz,    // xA..xB, 2*SS per batch
                                            float* __restrict__ part,
                                            int*   __restrict__ fincnt) {
    int b = blockIdx.x, tid = threadIdx.x;
    int* cb = cnt + b * NTAB;
    for (int i = tid; i < NTAB; i += 256) cb[i] = 0;
    float* xb = xz + b * 2 * SS;
#pragma unroll
    for (int i = 0; i < 2 * SS / 256; ++i) xb[tid + i * 256] = 0.0f;
    part[b * NT * NT + tid] = 0.0f;            // blockDim == NT*NT == 256
    if (b == 0 && tid == 0) *fincnt = 0;
    __syncthreads();
    atomicAdd(&cb[ul[b * LL + tid]], 1);
}

// ---------------------------------------------------------------------------
// D_t = exp(root_t) + link term + sum_{s!=t} exp(span).  ONE WAVE PER ROW,
// barrier-free, LDS-free.  ALSO materializes W8[t][s] = fp8(exp(span score))
// with diagonal zeroed.  D itself stays fp32-exact (sums fp32 exps).
__global__ __launch_bounds__(256) void kD(const float* __restrict__ scores,
                                          const int*   __restrict__ cand,
                                          const int*   __restrict__ cnt,
                                          float* __restrict__ invD,
                                          float* __restrict__ logD,
                                          unsigned char* __restrict__ W8) {
    int blk  = blockIdx.x;                 // 4096 blocks: b*256 + chunk-of-4
    int b    = blk >> 8;
    int lane = threadIdx.x & 63;
    int w    = threadIdx.x >> 6;           // wave 0..3 -> row
    int t    = ((blk & 255) << 2) + w;
    size_t bt = (size_t)b * SS + t;
    const float* rp = scores + bt * SCW;

    // issue all global loads up front; latency hides under the dedup loop
    float rt = rp[0];
    float xv[16];
#pragma unroll
    for (int q = 0; q < 16; ++q) xv[q] = rp[1 + CC + q * 64 + lane];

    int   c = lane & 15;
    int   v = -1 - lane;                   // unique non-id for lanes >= 16
    float scc = 0.0f;
    if (lane < 16) { v = cand[bt * CC + c]; scc = rp[1 + c]; }
    int m = (lane < 16) ? cnt[b * NTAB + v] : 0;

    int g = 0; float ssum = 0.0f; bool leader = (lane < 16);
#pragma unroll
    for (int j = 0; j < 16; ++j) {
        int   vj = __shfl(v,   j, 64);
        float sj = __shfl(scc, j, 64);
        bool  eq = (vj == v);
        g    += eq ? 1 : 0;
        ssum += eq ? sj : 0.0f;
        if (eq && j < c) leader = false;   // lowest-index holder of v leads
    }

    float acc = (leader && m) ? (float)(g * m) * expf(ssum) : 0.0f;
    unsigned char* wrow = W8 + bt * SS;
#pragma unroll
    for (int q = 0; q < 16; ++q) {
        int s = q * 64 + lane;
        float ev = (s != t) ? expf(xv[q]) : 0.0f;   // diag zeroed at source
        acc += ev;
        wrow[s] = enc8(ev);
    }
#pragma unroll
    for (int o = 32; o > 0; o >>= 1) acc += __shfl_xor(acc, o, 64);
    if (lane == 0) {
        float Dv = acc + expf(rt);
        invD[bt] = 1.0f / Dv;
        logD[bt] = logf(Dv);
    }
}

// ---------------------------------------------------------------------------
// FUSED tr2 + mv1 (cheap mirror).  Upper-tri tile pair (si <= ti):
//  tr2 partial: sum W[t][s]*W[s][t]*invD_t*invD_s  (off-diag doubled)
//  mv1 (z = invD): direct tile (rows ti, cols si): one extra FMA in the
//    main loop, 1 atomic per column at the end.
//  mirror tile (rows si, cols ti, si != ti): computed AFTER the loop by
//    re-reading the staged LDS tile along the other axis (stride 65 -> 2-way
//    bank aliasing = free), 4-wave partials combined via mred, 1 atomic/col.
//  Every ordered (row-tile, col-tile) pair covered exactly once -> x1 exact.
__global__ __launch_bounds__(256) void kTrMV1(const unsigned char* __restrict__ W8,
                                              const float* __restrict__ invD,
                                              float* __restrict__ part,
                                              float* __restrict__ x1) {
    int idx = blockIdx.x;                  // BB * NTRI blocks
    int b   = idx / NTRI;
    int r   = idx - b * NTRI;
    int ti  = (int)((sqrtf(8.0f * (float)r + 1.0f) - 1.0f) * 0.5f);
    while ((ti + 1) * (ti + 2) / 2 <= r) ++ti;   // float-safety correction
    while (ti * (ti + 1) / 2 > r) --ti;
    int si  = r - ti * (ti + 1) / 2;             // si <= ti

    int s0 = si * 64, t0 = ti * 64;
    const unsigned char* wb = W8 + (size_t)b * SS * SS;
    __shared__ float T2t[64][65];
    __shared__ float red[16];
    __shared__ float ivsh[64];
    __shared__ float mred[4][64];
    int tid  = threadIdx.x;
    int lane = tid & 63;
    int w    = tid >> 6;                   // wave id = row4

    // mirrored tile: T2t[i][j] = W(b, s0+j, t0+i)
#pragma unroll
    for (int q = 0; q < 16; ++q) {
        int j = q * 4 + w;
        T2t[lane][j] = dec8(wb[(size_t)(s0 + j) * SS + t0 + lane]);
    }
    if (tid < 64) ivsh[tid] = invD[b * SS + s0 + tid];
    __syncthreads();

    float ivs = ivsh[lane];
    float acc = 0.0f;          // tr2 partial
    float colacc = 0.0f;       // mv1 direct-tile partial for col s0+lane
    float* xo = x1 + b * SS;
#pragma unroll
    for (int q = 0; q < 16; ++q) {
        int i  = q * 4 + w;
        int tg = t0 + i;
        float ivt = invD[b * SS + tg];
        float a   = dec8(wb[(size_t)tg * SS + s0 + lane]);
        acc    += a * T2t[i][lane] * ivt * ivs;  // diag products 0 by construction
        colacc += a * ivt;
    }
    atomicAdd(&xo[s0 + lane], colacc);     // 4 waves -> 4 adds per column

    if (si != ti) {                        // mirror-tile mv1, LDS re-read
        float p = 0.0f;
#pragma unroll
        for (int k = 0; k < 16; ++k)
            p += T2t[lane][w * 16 + k] * ivsh[w * 16 + k];
        mred[w][lane] = p;
        __syncthreads();                   // uniform branch (si,ti block-uniform)
        if (w == 0) {
            float yv = mred[0][lane] + mred[1][lane] + mred[2][lane] + mred[3][lane];
            atomicAdd(&xo[t0 + lane], yv);
        }
    }

    float tot = blockReduceSum(acc, red);
    if (tid == 0) part[(b * NT + ti) * NT + si] = (si == ti) ? tot : 2.0f * tot;
}

// ---------------------------------------------------------------------------
// Partial matvec on fp8 W: x[b][s] += sum_t W[t][s] * z_t, z = xin*invD
// (xin==NULL => z = invD).  uchar4 loads (4 B/lane, 256 B/wave-instr): thread
// covers 4 adjacent cols 4*tid..4*tid+3 — halves load-instruction count vs
// uchar2 (the kernels are instruction-bound, not bytes-bound; round-13
// lesson).  No diag branch (W8 diag is zero).  Block (t0,b) is the only
// reader of xin[b][t0..t0+16): may zero that slice.
__global__ __launch_bounds__(256) void kMVh(const unsigned char* __restrict__ W8,
                                            const float* __restrict__ xin,
                                            const float* __restrict__ invD,
                                            float* __restrict__ xout,
                                            float* __restrict__ zeroSlice) {
    int b   = blockIdx.y;
    int t0  = blockIdx.x * TCH;
    int tid = threadIdx.x;
    __shared__ float zl[TCH];
    if (tid < TCH) {
        int i = b * SS + t0 + tid;
        float zz = invD[i];
        if (xin) zz *= xin[i];
        zl[tid] = zz;
    }
    __syncthreads();
    if (zeroSlice && tid < TCH) zeroSlice[b * SS + t0 + tid] = 0.0f;

    float a0 = 0.0f, a1 = 0.0f, a2 = 0.0f, a3 = 0.0f;
    const unsigned char* base = W8 + (size_t)(b * SS + t0) * SS + 4 * tid;
#pragma unroll
    for (int r = 0; r < TCH; ++r) {
        uchar4 u = *(const uchar4*)(base + (size_t)r * SS);
        float z = zl[r];
        a0 += dec8(u.x) * z; a1 += dec8(u.y) * z;
        a2 += dec8(u.z) * z; a3 += dec8(u.w) * z;
    }
    float* xo = xout + b * SS + 4 * tid;
    atomicAdd(&xo[0], a0);
    atomicAdd(&xo[1], a1);
    atomicAdd(&xo[2], a2);
    atomicAdd(&xo[3], a3);
}

// ---------------------------------------------------------------------------
// One block per batch: d34, d33, sum(logD), tr2 reduce, per-batch loss;
// last finishing block reduces bres -> out (threadfence+counter pattern).
__global__ __launch_bounds__(256) void kFinA(const float* __restrict__ x3,
                                             const float* __restrict__ x4,
                                             const float* __restrict__ logD,
                                             const float* __restrict__ part,
                                             float* __restrict__ bres,
                                             int*   __restrict__ fincnt,
                                             float* __restrict__ out) {
    int b = blockIdx.x;
    int tid = threadIdx.x;
    __shared__ float red[16];
    __shared__ int isLast;
    float pd34 = 0.0f, pd33 = 0.0f, pslg = 0.0f;
#pragma unroll
    for (int r = 0; r < 4; ++r) {
        int i = b * SS + r * 256 + tid;
        float a = x3[i], c = x4[i], lg = logD[i];
        pd34 += a * c; pd33 += a * a; pslg += lg;
    }
    float pv = part[b * NT * NT + tid];          // blockDim == NT*NT == 256
    float d34 = blockReduceSum(pd34, red);
    float d33 = blockReduceSum(pd33, red);
    float slg = blockReduceSum(pslg, red);
    float t2  = blockReduceSum(pv, red);
    if (tid == 0) {
        float lam = d34 / d33;
        bres[b] = slg + log1pf(-lam) + lam - 0.5f * (t2 - lam * lam);
    }
    __threadfence();
    if (tid == 0) isLast = (atomicAdd(fincnt, 1) == BB - 1);
    __syncthreads();
    if (isLast && tid < 64) {
        __threadfence();
        float v = (tid < BB) ? bres[tid] : 0.0f;
#pragma unroll
        for (int o = 32; o > 0; o >>= 1) v += __shfl_xor(v, o, 64);
        if (tid == 0) out[0] = v / (float)BB;
    }
}

// ---------------------------------------------------------------------------
extern "C" void kernel_launch(void* const* d_in, const int* in_sizes, int n_in,
                              void* d_out, int out_size, void* d_ws, size_t ws_size,
                              hipStream_t stream) {
    const float* scores = (const float*)d_in[0];
    const int*   cand   = (const int*)d_in[1];
    const int*   ul     = (const int*)d_in[2];
    float* out = (float*)d_out;

    float* ws   = (float*)d_ws;
    float* invD = ws;                   // BB*SS
    float* logD = invD + BB * SS;       // BB*SS
    float* xA   = logD + BB * SS;       // BB*SS  (x1, then x3)
    float* xB   = xA   + BB * SS;       // BB*SS  (x2, then x4)
    float* cntF = xB   + BB * SS;       // BB*NTAB ints
    float* part = cntF + BB * NTAB;     // BB*NT*NT (tr2 partials)
    float* bres = part + BB * NT * NT;  // 64 (BB used)
    int*   fincnt = (int*)(bres + 64);  // completion counter
    float* whF  = bres + 80;            // fp8 W: BB*SS*SS bytes (16B-aligned)
    int*   cnt  = (int*)cntF;
    unsigned char* W8 = (unsigned char*)whF;

    // 1: per-batch zeroing (cnt, xA/xB, part, fincnt) + link multiplicities
    kCnt<<<dim3(BB), dim3(256), 0, stream>>>(ul, cnt, xA, part, fincnt);
    // 2: column sums D (fp32-exact) + materialize W8 = fp8(exp), diag zeroed
    kD<<<dim3(BB * SS / 4), dim3(256), 0, stream>>>(scores, cand, cnt, invD, logD, W8);
    // 3: tr(R^2) tiles FUSED with mv1 (cheap LDS mirror) -> part, x1 = xA
    kTrMV1<<<dim3(BB * NTRI), dim3(256), 0, stream>>>(W8, invD, part, xA);
    // 4-6: power iteration x2..x4 (re-zero folded into the last reader)
    dim3 mvGrid(NCH, BB);
    kMVh<<<mvGrid, dim3(256), 0, stream>>>(W8, xA, invD, xB, xA);              // x2 -> xB, zero xA
    kMVh<<<mvGrid, dim3(256), 0, stream>>>(W8, xB, invD, xA, xB);              // x3 -> xA, zero xB
    kMVh<<<mvGrid, dim3(256), 0, stream>>>(W8, xA, invD, xB, (float*)nullptr); // x4 -> xB (keep xA)
    // 7: per-batch finish + last-block global reduce
    kFinA<<<dim3(BB), dim3(256), 0, stream>>>(xA, xB, logD, part, bres, fincnt, out);
}

// Round 15
// 76.291 us; speedup vs baseline: 1.3318x; 1.3318x over previous
//
#include <hip/hip_runtime.h>
#include <math.h>

// Problem constants (fixed by setup_inputs)
#define BB  16      // batch
#define SS  1024    // spans
#define CC  16      // candidates per span
#define LL  256     // unique links
#define SCW 1041    // 1 + CC + SS  (scores row width)
#define NTAB 5000   // candidate/link id space

#define TCH 16                    // t-rows per matvec chunk
#define NCH (SS / TCH)            // 64 chunks per batch
#define NT  (SS / 64)             // 16 tiles per axis in tr2
#define NTRI (NT * (NT + 1) / 2)  // 136 upper-tri tiles per batch

// ---------------------------------------------------------------------------
// fp8 e4m3 (OCP) encode/decode, self-contained bit ops.  Our W values are
// either exactly 0 (diag) or in [~0.05, ~16] -- always e4m3-normal.
// encode: RNE into 3-bit mantissa; flush-to-zero below 2^-6 (unreachable).
__device__ __forceinline__ unsigned char enc8(float f) {
    unsigned u = __float_as_uint(f);
    if (u < 0x3C800000u) return 0;       // < 2^-6 (incl. exact 0) -> 0
    u += 0x7FFFFu + ((u >> 20) & 1u);    // round-to-nearest-even into man3
    return (unsigned char)((u >> 20) - 960u);   // ((e8-120)<<3)|man3
}
// decode: byte b = (e<<3)|m (e>=1)  ->  f32 bits ((e+120)<<23)|(m<<20)
__device__ __forceinline__ float dec8(unsigned char b) {
    return b ? __uint_as_float(((unsigned)b + 960u) << 20) : 0.0f;
}

// ---------------------------------------------------------------------------
// block-wide sum reduction (blockDim multiple of 64, <=1024), lds >= 16 floats
__device__ __forceinline__ float blockReduceSum(float v, float* lds) {
#pragma unroll
    for (int o = 32; o > 0; o >>= 1) v += __shfl_down(v, o, 64);
    int lane = threadIdx.x & 63;
    int wid  = threadIdx.x >> 6;
    int nw   = blockDim.x >> 6;
    if (lane == 0) lds[wid] = v;
    __syncthreads();
    v = (threadIdx.x < nw) ? lds[threadIdx.x] : 0.0f;
    if (wid == 0) {
#pragma unroll
        for (int o = 8; o > 0; o >>= 1) v += __shfl_down(v, o, 64);
        if (lane == 0) lds[0] = v;
    }
    __syncthreads();
    v = lds[0];
    __syncthreads();
    return v;
}

// ---------------------------------------------------------------------------
// Per-batch setup: block b zeroes its own cnt slice, xA/xB slices, part slice;
// then counts link multiplicities.
__global__ __launch_bounds__(256) void kCnt(const int* __restrict__ ul,
                                            int*   __restrict__ cnt,
                                            float* __restrict__ xz,    // xA..xB, 2*SS per batch
                                            float* __restrict__ part,
                                            int*   __restrict__ fincnt) {
    int b = blockIdx.x, tid = threadIdx.x;
    int* cb = cnt + b * NTAB;
    for (int i = tid; i < NTAB; i += 256) cb[i] = 0;
    float* xb = xz + b * 2 * SS;
#pragma unroll
    for (int i = 0; i < 2 * SS / 256; ++i) xb[tid + i * 256] = 0.0f;
    part[b * NT * NT + tid] = 0.0f;            // blockDim == NT*NT == 256
    if (b == 0 && tid == 0) *fincnt = 0;
    __syncthreads();
    atomicAdd(&cb[ul[b * LL + tid]], 1);
}

// ---------------------------------------------------------------------------
// D_t = exp(root_t) + link term + sum_{s!=t} exp(span).  ONE WAVE PER ROW,
// barrier-free, LDS-free.  ALSO materializes W8[t][s] = fp8(exp(span score))
// with diagonal zeroed.  D itself stays fp32-exact (sums fp32 exps).
__global__ __launch_bounds__(256) void kD(const float* __restrict__ scores,
                                          const int*   __restrict__ cand,
                                          const int*   __restrict__ cnt,
                                          float* __restrict__ invD,
                                          float* __restrict__ logD,
                                          unsigned char* __restrict__ W8) {
    int blk  = blockIdx.x;                 // 4096 blocks: b*256 + chunk-of-4
    int b    = blk >> 8;
    int lane = threadIdx.x & 63;
    int w    = threadIdx.x >> 6;           // wave 0..3 -> row
    int t    = ((blk & 255) << 2) + w;
    size_t bt = (size_t)b * SS + t;
    const float* rp = scores + bt * SCW;

    // issue all global loads up front; latency hides under the dedup loop
    float rt = rp[0];
    float xv[16];
#pragma unroll
    for (int q = 0; q < 16; ++q) xv[q] = rp[1 + CC + q * 64 + lane];

    int   c = lane & 15;
    int   v = -1 - lane;                   // unique non-id for lanes >= 16
    float scc = 0.0f;
    if (lane < 16) { v = cand[bt * CC + c]; scc = rp[1 + c]; }
    int m = (lane < 16) ? cnt[b * NTAB + v] : 0;

    int g = 0; float ssum = 0.0f; bool leader = (lane < 16);
#pragma unroll
    for (int j = 0; j < 16; ++j) {
        int   vj = __shfl(v,   j, 64);
        float sj = __shfl(scc, j, 64);
        bool  eq = (vj == v);
        g    += eq ? 1 : 0;
        ssum += eq ? sj : 0.0f;
        if (eq && j < c) leader = false;   // lowest-index holder of v leads
    }

    float acc = (leader && m) ? (float)(g * m) * expf(ssum) : 0.0f;
    unsigned char* wrow = W8 + bt * SS;
#pragma unroll
    for (int q = 0; q < 16; ++q) {
        int s = q * 64 + lane;
        float ev = (s != t) ? expf(xv[q]) : 0.0f;   // diag zeroed at source
        acc += ev;
        wrow[s] = enc8(ev);
    }
#pragma unroll
    for (int o = 32; o > 0; o >>= 1) acc += __shfl_xor(acc, o, 64);
    if (lane == 0) {
        float Dv = acc + expf(rt);
        invD[bt] = 1.0f / Dv;
        logD[bt] = logf(Dv);
    }
}

// ---------------------------------------------------------------------------
// FUSED tr2 + mv1 (cheap mirror).  Upper-tri tile pair (si <= ti):
//  tr2 partial: sum W[t][s]*W[s][t]*invD_t*invD_s  (off-diag doubled)
//  mv1 (z = invD): direct tile (rows ti, cols si): one extra FMA in the
//    main loop, 1 atomic per column at the end.
//  mirror tile (rows si, cols ti, si != ti): computed AFTER the loop by
//    re-reading the staged LDS tile along the other axis (stride 65 -> 2-way
//    bank aliasing = free), 4-wave partials combined via mred, 1 atomic/col.
//  Every ordered (row-tile, col-tile) pair covered exactly once -> x1 exact.
__global__ __launch_bounds__(256) void kTrMV1(const unsigned char* __restrict__ W8,
                                              const float* __restrict__ invD,
                                              float* __restrict__ part,
                                              float* __restrict__ x1) {
    int idx = blockIdx.x;                  // BB * NTRI blocks
    int b   = idx / NTRI;
    int r   = idx - b * NTRI;
    int ti  = (int)((sqrtf(8.0f * (float)r + 1.0f) - 1.0f) * 0.5f);
    while ((ti + 1) * (ti + 2) / 2 <= r) ++ti;   // float-safety correction
    while (ti * (ti + 1) / 2 > r) --ti;
    int si  = r - ti * (ti + 1) / 2;             // si <= ti

    int s0 = si * 64, t0 = ti * 64;
    const unsigned char* wb = W8 + (size_t)b * SS * SS;
    __shared__ float T2t[64][65];
    __shared__ float red[16];
    __shared__ float ivsh[64];
    __shared__ float mred[4][64];
    int tid  = threadIdx.x;
    int lane = tid & 63;
    int w    = tid >> 6;                   // wave id = row4

    // mirrored tile: T2t[i][j] = W(b, s0+j, t0+i)
#pragma unroll
    for (int q = 0; q < 16; ++q) {
        int j = q * 4 + w;
        T2t[lane][j] = dec8(wb[(size_t)(s0 + j) * SS + t0 + lane]);
    }
    if (tid < 64) ivsh[tid] = invD[b * SS + s0 + tid];
    __syncthreads();

    float ivs = ivsh[lane];
    float acc = 0.0f;          // tr2 partial
    float colacc = 0.0f;       // mv1 direct-tile partial for col s0+lane
    float* xo = x1 + b * SS;
#pragma unroll
    for (int q = 0; q < 16; ++q) {
        int i  = q * 4 + w;
        int tg = t0 + i;
        float ivt = invD[b * SS + tg];
        float a   = dec8(wb[(size_t)tg * SS + s0 + lane]);
        acc    += a * T2t[i][lane] * ivt * ivs;  // diag products 0 by construction
        colacc += a * ivt;
    }
    atomicAdd(&xo[s0 + lane], colacc);     // 4 waves -> 4 adds per column

    if (si != ti) {                        // mirror-tile mv1, LDS re-read
        float p = 0.0f;
#pragma unroll
        for (int k = 0; k < 16; ++k)
            p += T2t[lane][w * 16 + k] * ivsh[w * 16 + k];
        mred[w][lane] = p;
        __syncthreads();                   // uniform branch (si,ti block-uniform)
        if (w == 0) {
            float yv = mred[0][lane] + mred[1][lane] + mred[2][lane] + mred[3][lane];
            atomicAdd(&xo[t0 + lane], yv);
        }
    }

    float tot = blockReduceSum(acc, red);
    if (tid == 0) part[(b * NT + ti) * NT + si] = (si == ti) ? tot : 2.0f * tot;
}

// ---------------------------------------------------------------------------
// Partial matvec on fp8 W: x[b][s] += sum_t W[t][s] * z_t, z = xin*invD
// (xin==NULL => z = invD).  uchar2 loads: thread covers cols {2tid,2tid+1,
// 512+2tid,512+2tid+1} (the proven mapping; uchar4/adjacent-4 regressed
// 76.6->101.6 in round 14 -- do not "widen" this loop).  No diag branch
// (W8 diag is zero).  Block (t0,b) is the only reader of xin[b][t0..t0+16):
// may zero that slice.
__global__ __launch_bounds__(256) void kMVh(const unsigned char* __restrict__ W8,
                                            const float* __restrict__ xin,
                                            const float* __restrict__ invD,
                                            float* __restrict__ xout,
                                            float* __restrict__ zeroSlice) {
    int b   = blockIdx.y;
    int t0  = blockIdx.x * TCH;
    int tid = threadIdx.x;
    __shared__ float zl[TCH];
    if (tid < TCH) {
        int i = b * SS + t0 + tid;
        float zz = invD[i];
        if (xin) zz *= xin[i];
        zl[tid] = zz;
    }
    __syncthreads();
    if (zeroSlice && tid < TCH) zeroSlice[b * SS + t0 + tid] = 0.0f;

    float a00 = 0.0f, a01 = 0.0f, a10 = 0.0f, a11 = 0.0f;
    const unsigned char* base = W8 + (size_t)(b * SS + t0) * SS;
#pragma unroll
    for (int r = 0; r < TCH; ++r) {
        const uchar2* rp = (const uchar2*)(base + (size_t)r * SS);
        float z = zl[r];
        uchar2 lo = rp[tid];
        uchar2 hi = rp[tid + 256];
        a00 += dec8(lo.x) * z; a01 += dec8(lo.y) * z;
        a10 += dec8(hi.x) * z; a11 += dec8(hi.y) * z;
    }
    float* xo = xout + b * SS;
    atomicAdd(&xo[2 * tid],           a00);
    atomicAdd(&xo[2 * tid + 1],       a01);
    atomicAdd(&xo[512 + 2 * tid],     a10);
    atomicAdd(&xo[512 + 2 * tid + 1], a11);
}

// ---------------------------------------------------------------------------
// One block per batch: d34, d33, sum(logD), tr2 reduce, per-batch loss;
// last finishing block reduces bres -> out (threadfence+counter pattern).
__global__ __launch_bounds__(256) void kFinA(const float* __restrict__ x3,
                                             const float* __restrict__ x4,
                                             const float* __restrict__ logD,
                                             const float* __restrict__ part,
                                             float* __restrict__ bres,
                                             int*   __restrict__ fincnt,
                                             float* __restrict__ out) {
    int b = blockIdx.x;
    int tid = threadIdx.x;
    __shared__ float red[16];
    __shared__ int isLast;
    float pd34 = 0.0f, pd33 = 0.0f, pslg = 0.0f;
#pragma unroll
    for (int r = 0; r < 4; ++r) {
        int i = b * SS + r * 256 + tid;
        float a = x3[i], c = x4[i], lg = logD[i];
        pd34 += a * c; pd33 += a * a; pslg += lg;
    }
    float pv = part[b * NT * NT + tid];          // blockDim == NT*NT == 256
    float d34 = blockReduceSum(pd34, red);
    float d33 = blockReduceSum(pd33, red);
    float slg = blockReduceSum(pslg, red);
    float t2  = blockReduceSum(pv, red);
    if (tid == 0) {
        float lam = d34 / d33;
        bres[b] = slg + log1pf(-lam) + lam - 0.5f * (t2 - lam * lam);
    }
    __threadfence();
    if (tid == 0) isLast = (atomicAdd(fincnt, 1) == BB - 1);
    __syncthreads();
    if (isLast && tid < 64) {
        __threadfence();
        float v = (tid < BB) ? bres[tid] : 0.0f;
#pragma unroll
        for (int o = 32; o > 0; o >>= 1) v += __shfl_xor(v, o, 64);
        if (tid == 0) out[0] = v / (float)BB;
    }
}

// ---------------------------------------------------------------------------
extern "C" void kernel_launch(void* const* d_in, const int* in_sizes, int n_in,
                              void* d_out, int out_size, void* d_ws, size_t ws_size,
                              hipStream_t stream) {
    const float* scores = (const float*)d_in[0];
    const int*   cand   = (const int*)d_in[1];
    const int*   ul     = (const int*)d_in[2];
    float* out = (float*)d_out;

    float* ws   = (float*)d_ws;
    float* invD = ws;                   // BB*SS
    float* logD = invD + BB * SS;       // BB*SS
    float* xA   = logD + BB * SS;       // BB*SS  (x1, then x3)
    float* xB   = xA   + BB * SS;       // BB*SS  (x2, then x4)
    float* cntF = xB   + BB * SS;       // BB*NTAB ints
    float* part = cntF + BB * NTAB;     // BB*NT*NT (tr2 partials)
    float* bres = part + BB * NT * NT;  // 64 (BB used)
    int*   fincnt = (int*)(bres + 64);  // completion counter
    float* whF  = bres + 80;            // fp8 W: BB*SS*SS bytes (16B-aligned)
    int*   cnt  = (int*)cntF;
    unsigned char* W8 = (unsigned char*)whF;

    // 1: per-batch zeroing (cnt, xA/xB, part, fincnt) + link multiplicities
    kCnt<<<dim3(BB), dim3(256), 0, stream>>>(ul, cnt, xA, part, fincnt);
    // 2: column sums D (fp32-exact) + materialize W8 = fp8(exp), diag zeroed
    kD<<<dim3(BB * SS / 4), dim3(256), 0, stream>>>(scores, cand, cnt, invD, logD, W8);
    // 3: tr(R^2) tiles FUSED with mv1 (cheap LDS mirror) -> part, x1 = xA
    kTrMV1<<<dim3(BB * NTRI), dim3(256), 0, stream>>>(W8, invD, part, xA);
    // 4-6: power iteration x2..x4 (re-zero folded into the last reader)
    dim3 mvGrid(NCH, BB);
    kMVh<<<mvGrid, dim3(256), 0, stream>>>(W8, xA, invD, xB, xA);              // x2 -> xB, zero xA
    kMVh<<<mvGrid, dim3(256), 0, stream>>>(W8, xB, invD, xA, xB);              // x3 -> xA, zero xB
    kMVh<<<mvGrid, dim3(256), 0, stream>>>(W8, xA, invD, xB, (float*)nullptr); // x4 -> xB (keep xA)
    // 7: per-batch finish + last-block global reduce
    kFinA<<<dim3(BB), dim3(256), 0, stream>>>(xA, xB, logD, part, bres, fincnt, out);
}